// Round 1
// baseline (375.880 us; speedup 1.0000x reference)
//
#include <hip/hip_runtime.h>
#include <hip/hip_bf16.h>
#include <math.h>

#define T_ 6
#define LQ_ 300
#define C_ 256
#define NH_ 8
#define HD_ 32
#define DFF_ 1024
#define LIN_ 16320
#define NQ_ (T_*LQ_)   /* 1800 */

typedef unsigned int uint32;
typedef unsigned short us;

__device__ __forceinline__ float b2f(us u) {
    union { float f; unsigned i; } x; x.i = ((unsigned)u) << 16; return x.f;
}
__device__ __forceinline__ us f2b(float f) {
    union { float f; unsigned i; } x; x.f = f;
    unsigned r = x.i + 0x7fffu + ((x.i >> 16) & 1u);
    return (us)(r >> 16);
}
__device__ __forceinline__ uint32 pack2(float a, float b) {
    union { __hip_bfloat162 h; uint32 u; } c;
    c.h = __float22bfloat162_rn(make_float2(a, b));
    return c.u;
}

typedef __bf16 bf16x8 __attribute__((ext_vector_type(8)));
typedef float  f32x4  __attribute__((ext_vector_type(4)));

// LDS leading dim (us units) for a 64x256 bf16 A tile. 264 = 256+8:
// 264*2B = 528B row stride = 4*odd dwords -> same 8-way-max bank class as
// the verified LDA=40 layout, and keeps 16B alignment (528 = 16*33).
#define LDA2 264

// bf16 weight arena offsets (us elements)
#define WOFF_VAL   0
#define WOFF_IN    65536
#define WOFF_SA    262144
#define WOFF_SOFF  327680
#define WOFF_TOFF  393216
#define WOFF_ATTN  458752
#define WOFF_CROSS 524288
#define WOFF_LIN1  589824
#define WOFF_LIN2  851968
#define WTOTAL     1114112

// ---------------------------------------------------------------------------
// One-time fp32 -> bf16 weight conversion. grid = (128, 9).
// Removes all B-side pack2 VALU from every GEMM and halves B traffic.
// ---------------------------------------------------------------------------
__global__ __launch_bounds__(256) void cvt_kernel(
        const float* __restrict__ w0, const float* __restrict__ w1,
        const float* __restrict__ w2, const float* __restrict__ w3,
        const float* __restrict__ w4, const float* __restrict__ w5,
        const float* __restrict__ w6, const float* __restrict__ w7,
        const float* __restrict__ w8, us* __restrict__ dst) {
    int y = blockIdx.y;
    const float* s; int n; int off;
    switch (y) {
        case 0: s = w0; n = 65536;  off = WOFF_VAL;   break;
        case 1: s = w1; n = 196608; off = WOFF_IN;    break;
        case 2: s = w2; n = 65536;  off = WOFF_SA;    break;
        case 3: s = w3; n = 65536;  off = WOFF_SOFF;  break;
        case 4: s = w4; n = 65536;  off = WOFF_TOFF;  break;
        case 5: s = w5; n = 65536;  off = WOFF_ATTN;  break;
        case 6: s = w6; n = 65536;  off = WOFF_CROSS; break;
        case 7: s = w7; n = 262144; off = WOFF_LIN1;  break;
        default: s = w8; n = 262144; off = WOFF_LIN2; break;
    }
    int i = (blockIdx.x * 256 + threadIdx.x) * 8;
    if (i >= n) return;
    float4 a = *(const float4*)(s + i);
    float4 b = *(const float4*)(s + i + 4);
    uint4 p;
    p.x = pack2(a.x, a.y); p.y = pack2(a.z, a.w);
    p.z = pack2(b.x, b.y); p.w = pack2(b.z, b.w);
    *(uint4*)(dst + off + i) = p;
}

// ---------------------------------------------------------------------------
// 64x64-tile GEMM v2: per 256-K-chunk, full A sub-tile staged once to LDS
// (fp32 load + pack), then barrier-free inner loop reading bf16 B fragments
// DIRECTLY from global (weights are L2-resident). 2 barriers per 256-K-chunk
// instead of 16.
// ---------------------------------------------------------------------------
__device__ __forceinline__ void gemm64_core(
        us* As, int bm,
        const float* __restrict__ A, const float* __restrict__ A2,
        const us* __restrict__ Bw,   // bf16 weights, row n = Bw + n*K
        const float* __restrict__ bias, float* __restrict__ Cmat,
        int ldc, int cn0, int M, int K, bool relu) {
    int tid  = threadIdx.x;
    int wave = tid >> 6, lane = tid & 63;
    int wm = (wave >> 1) * 32, wn = (wave & 1) * 32;
    int fr = lane & 15, quad = lane >> 4;

    f32x4 acc00 = {0.f,0.f,0.f,0.f}, acc01 = {0.f,0.f,0.f,0.f};
    f32x4 acc10 = {0.f,0.f,0.f,0.f}, acc11 = {0.f,0.f,0.f,0.f};

    const us* pa0 = As + (wm + fr) * LDA2 + quad * 8;
    const us* pa1 = pa0 + 16 * LDA2;
    const us* pb0 = Bw + (size_t)(wn + fr) * K + quad * 8;
    const us* pb1 = pb0 + (size_t)16 * K;

    for (int k0 = 0; k0 < K; k0 += 256) {
        if (k0) __syncthreads();
        // stage A (+A2) 64x256 fp32 -> bf16 LDS; 8 uint4 stores per thread
        #pragma unroll
        for (int u = 0; u < 8; ++u) {
            int f = u * 256 + tid;
            int row = f >> 5, c8 = (f & 31) * 8;
            int arow = bm + row;
            float4 p0 = make_float4(0.f,0.f,0.f,0.f), p1 = p0;
            if (arow < M) {
                const float* ap = A + (size_t)arow * K + k0 + c8;
                p0 = *(const float4*)ap;
                p1 = *(const float4*)(ap + 4);
                if (A2) {
                    const float* aq = A2 + (size_t)arow * K + k0 + c8;
                    float4 q0 = *(const float4*)aq, q1 = *(const float4*)(aq + 4);
                    p0.x += q0.x; p0.y += q0.y; p0.z += q0.z; p0.w += q0.w;
                    p1.x += q1.x; p1.y += q1.y; p1.z += q1.z; p1.w += q1.w;
                }
            }
            uint4 w;
            w.x = pack2(p0.x, p0.y); w.y = pack2(p0.z, p0.w);
            w.z = pack2(p1.x, p1.y); w.w = pack2(p1.z, p1.w);
            *(uint4*)(As + row * LDA2 + c8) = w;
        }
        __syncthreads();
        // inner loop: B fragments direct from global bf16, 1-deep prefetch
        bf16x8 b0 = *(const bf16x8*)(pb0 + k0);
        bf16x8 b1 = *(const bf16x8*)(pb1 + k0);
        #pragma unroll
        for (int c = 0; c < 8; ++c) {
            int kk = c * 32;
            int kkn = (c < 7) ? kk + 32 : 0;
            bf16x8 nb0 = *(const bf16x8*)(pb0 + k0 + kkn);
            bf16x8 nb1 = *(const bf16x8*)(pb1 + k0 + kkn);
            bf16x8 a0 = *(const bf16x8*)(pa0 + kk);
            bf16x8 a1 = *(const bf16x8*)(pa1 + kk);
            acc00 = __builtin_amdgcn_mfma_f32_16x16x32_bf16(a0, b0, acc00, 0, 0, 0);
            acc01 = __builtin_amdgcn_mfma_f32_16x16x32_bf16(a0, b1, acc01, 0, 0, 0);
            acc10 = __builtin_amdgcn_mfma_f32_16x16x32_bf16(a1, b0, acc10, 0, 0, 0);
            acc11 = __builtin_amdgcn_mfma_f32_16x16x32_bf16(a1, b1, acc11, 0, 0, 0);
            b0 = nb0; b1 = nb1;
        }
    }

    // C/D layout: n = lane&15, m = quad*4 + reg  [measured m89/m91]
    int n0l = wn + fr, n1l = n0l + 16;
    float bias0 = bias[n0l], bias1 = bias[n1l];
    int mbase = bm + wm + quad * 4;
    #pragma unroll
    for (int r = 0; r < 4; ++r) {
        int m0 = mbase + r, m1 = m0 + 16;
        float v00 = acc00[r] + bias0, v01 = acc01[r] + bias1;
        float v10 = acc10[r] + bias0, v11 = acc11[r] + bias1;
        if (relu) {
            v00 = fmaxf(v00, 0.f); v01 = fmaxf(v01, 0.f);
            v10 = fmaxf(v10, 0.f); v11 = fmaxf(v11, 0.f);
        }
        if (m0 < M) {
            Cmat[(size_t)m0 * ldc + cn0 + n0l] = v00;
            Cmat[(size_t)m0 * ldc + cn0 + n1l] = v01;
        }
        if (m1 < M) {
            Cmat[(size_t)m1 * ldc + cn0 + n0l] = v10;
            Cmat[(size_t)m1 * ldc + cn0 + n1l] = v11;
        }
    }
}

template<bool RELU>
__global__ __launch_bounds__(256, 2) void gemm_std(
        const float* __restrict__ A, const us* __restrict__ W,
        const float* __restrict__ bias, float* __restrict__ C,
        int M, int N, int K) {
    __shared__ __align__(16) us As[64 * LDA2];
    int cn0 = blockIdx.y * 64;
    gemm64_core(As, blockIdx.x * 64, A, nullptr, W + (size_t)cn0 * K, bias + cn0,
                C, N, cn0, M, K, RELU);
}

// fused soff/toff/attn-weight projections from qc. grid.y = 12.
__global__ __launch_bounds__(256, 2) void gemm_proj3(
        const float* __restrict__ qc,
        const us* __restrict__ sw, const float* __restrict__ sb,
        const us* __restrict__ tw, const float* __restrict__ tb,
        const us* __restrict__ aw, const float* __restrict__ ab,
        float* __restrict__ so, float* __restrict__ to, float* __restrict__ ao) {
    __shared__ __align__(16) us As[64 * LDA2];
    int y = blockIdx.y, g = y >> 2, cn0 = (y & 3) * 64;
    const us* W; const float* bias; float* O;
    if (g == 0)      { W = sw; bias = sb; O = so; }
    else if (g == 1) { W = tw; bias = tb; O = to; }
    else             { W = aw; bias = ab; O = ao; }
    gemm64_core(As, blockIdx.x * 64, qc, nullptr, W + (size_t)cn0 * 256, bias + cn0,
                O, 256, cn0, NQ_, 256, false);
}

// ---------------------------------------------------------------------------
// Fused dispatch #1: blocks [0,1530) = value projection, v3 structure:
// stage full 64x256 A tile ONCE (16 float4/thread in flight -> deep HBM
// pipeline), one barrier, then barrier-free K-loop with bf16 B fragments
// read directly from global (weights L2-resident, 1-deep prefetch).
// Blocks [1530,1878) = qkv projection tiles (q = tgt+qpos fused).
// ---------------------------------------------------------------------------
__global__ __launch_bounds__(256, 3) void vqkv_kernel(
        const float* __restrict__ src, const us* __restrict__ wval,
        const float* __restrict__ val_b, us* __restrict__ value,
        const float* __restrict__ tgt, const float* __restrict__ qpos,
        const us* __restrict__ w_in, const float* __restrict__ in_b,
        float* __restrict__ qkb, float* __restrict__ vbuf) {
    __shared__ __align__(16) us As[64 * LDA2];   // 33792 B
    if (blockIdx.x >= 1530) {
        // ---- qkv tile
        int u = blockIdx.x - 1530, y = u / 29, bm = (u % 29) * 64;
        if (y < 8)
            gemm64_core(As, bm, tgt, qpos, w_in + (size_t)y * 64 * 256,
                        in_b + y * 64, qkb, 512, y * 64, NQ_, 256, false);
        else
            gemm64_core(As, bm, tgt, nullptr,
                        w_in + (size_t)(512 + (y - 8) * 64) * 256,
                        in_b + 512 + (y - 8) * 64, vbuf, 256, (y - 8) * 64,
                        NQ_, 256, false);
        return;
    }
    // ---- value tile: 64 rows x 256 cols (all rows valid: 1530*64 = T*LIN)
    int tid = threadIdx.x, wave = tid >> 6, lane = tid & 63;
    int bm = blockIdx.x * 64;
    int fr = lane & 15, quad = lane >> 4;

    // stage A: full 64x256 fp32 -> bf16 LDS, all 16 float4 loads in flight
    #pragma unroll
    for (int u = 0; u < 8; ++u) {
        int f = u * 256 + tid;
        int row = f >> 5, c8 = (f & 31) * 8;
        const float* ap = src + (size_t)(bm + row) * 256 + c8;
        float4 p0 = *(const float4*)ap;
        float4 p1 = *(const float4*)(ap + 4);
        uint4 w;
        w.x = pack2(p0.x, p0.y); w.y = pack2(p0.z, p0.w);
        w.z = pack2(p1.x, p1.y); w.w = pack2(p1.z, p1.w);
        *(uint4*)(As + row * LDA2 + c8) = w;
    }
    __syncthreads();

    f32x4 acc[4][4];
    #pragma unroll
    for (int i = 0; i < 4; ++i)
        #pragma unroll
        for (int j = 0; j < 4; ++j) { f32x4 z = {0.f,0.f,0.f,0.f}; acc[i][j] = z; }

    // B fragment base: wave owns 64 output cols; row n = wave*64 + nt*16 + fr
    const us* bb = wval + (size_t)(wave * 64 + fr) * 256 + quad * 8;
    bf16x8 bcur[4];
    #pragma unroll
    for (int nt = 0; nt < 4; ++nt)
        bcur[nt] = *(const bf16x8*)(bb + nt * 16 * 256);

    for (int c = 0; c < 8; ++c) {
        int kk = c * 32;
        int kkn = (c < 7) ? kk + 32 : 0;
        bf16x8 bnext[4];
        #pragma unroll
        for (int nt = 0; nt < 4; ++nt)
            bnext[nt] = *(const bf16x8*)(bb + nt * 16 * 256 + kkn);
        bf16x8 af[4];
        #pragma unroll
        for (int mt = 0; mt < 4; ++mt)
            af[mt] = *(const bf16x8*)(As + (mt * 16 + fr) * LDA2 + kk + quad * 8);
        #pragma unroll
        for (int mt = 0; mt < 4; ++mt)
            #pragma unroll
            for (int nt = 0; nt < 4; ++nt)
                acc[mt][nt] = __builtin_amdgcn_mfma_f32_16x16x32_bf16(af[mt], bcur[nt], acc[mt][nt], 0, 0, 0);
        #pragma unroll
        for (int nt = 0; nt < 4; ++nt) bcur[nt] = bnext[nt];
    }

    // Epilogue: stage bf16 C tile in LDS (overlaying As), then coalesced
    // dwordx4 global stores (16 B/lane).
    __syncthreads();
    us* Cs = As;   // 64 x 256 us = 32768 B <= 33792 B
    #pragma unroll
    for (int nt = 0; nt < 4; ++nt) {
        int n = wave * 64 + nt * 16 + fr;
        float bs = val_b[n];
        #pragma unroll
        for (int mt = 0; mt < 4; ++mt) {
            int rowb = mt * 16 + quad * 4;
            #pragma unroll
            for (int r = 0; r < 4; ++r)
                Cs[(rowb + r) * 256 + n] = f2b(acc[mt][nt][r] + bs);
        }
    }
    __syncthreads();
    #pragma unroll
    for (int p = 0; p < 4; ++p) {
        int flat = p * 256 + tid;
        int row = flat >> 5, c16 = (flat & 31) * 8;
        uint4 v = *(const uint4*)(Cs + row * 256 + c16);
        *(uint4*)(value + (size_t)(bm + row) * 256 + c16) = v;
    }
}

// ---------------------------------------------------------------------------
// Self-attention (unchanged — verified rounds 2-6)
// ---------------------------------------------------------------------------
__global__ __launch_bounds__(256) void attn_kernel(
        const float* __restrict__ qk, const float* __restrict__ vb,
        float* __restrict__ sain) {
    __shared__ uint32 Ksu[300 * 17];
    __shared__ uint32 Vsu[300 * 17];
    __shared__ float  Qs[32 * 32];
    __shared__ float  ps[4][304];
    int t = blockIdx.x / NH_, h = blockIdx.x % NH_;
    int q0 = blockIdx.y * 32;
    int tid = threadIdx.x;

    for (int idx = tid; idx < 300 * 16; idx += 256) {
        int row = idx >> 4, cc = idx & 15;
        float2 kv = *(const float2*)(qk + (size_t)(t * 300 + row) * 512 + 256 + h * 32 + 2 * cc);
        float2 vv = *(const float2*)(vb + (size_t)(t * 300 + row) * 256 + h * 32 + 2 * cc);
        Ksu[row * 17 + cc] = pack2(kv.x, kv.y);
        Vsu[row * 17 + cc] = pack2(vv.x, vv.y);
    }
    for (int idx = tid; idx < 1024; idx += 256) {
        int row = idx >> 5, d = idx & 31;
        int q = q0 + row;
        Qs[idx] = (q < 300) ? qk[(size_t)(t * 300 + q) * 512 + h * 32 + d] : 0.f;
    }
    __syncthreads();

    int wavei = tid >> 6, lane = tid & 63;
    const float scale = 0.17677669529663687f;  // 1/sqrt(32)

    for (int i = 0; i < 8; ++i) {
        int q = q0 + wavei * 8 + i;
        int ql = wavei * 8 + i;
        float qv[32];
        #pragma unroll
        for (int d = 0; d < 32; ++d) qv[d] = Qs[ql * 32 + d];

        float sc[5], mx = -1e30f;
        #pragma unroll
        for (int m = 0; m < 5; ++m) {
            int k = lane + 64 * m;
            float s = -1e30f;
            if (k < 300) {
                s = 0.f;
                #pragma unroll
                for (int dd = 0; dd < 16; ++dd) {
                    uint32 u = Ksu[k * 17 + dd];
                    s += qv[2 * dd]     * b2f((us)u)
                       + qv[2 * dd + 1] * b2f((us)(u >> 16));
                }
                s *= scale;
            }
            sc[m] = s; mx = fmaxf(mx, s);
        }
        #pragma unroll
        for (int off = 1; off < 64; off <<= 1) mx = fmaxf(mx, __shfl_xor(mx, off));
        float sum = 0.f;
        #pragma unroll
        for (int m = 0; m < 5; ++m) {
            int k = lane + 64 * m;
            float ev = (k < 300) ? __expf(sc[m] - mx) : 0.f;
            if (k < 300) ps[wavei][k] = ev;
            sum += ev;
        }
        #pragma unroll
        for (int off = 1; off < 64; off <<= 1) sum += __shfl_xor(sum, off);
        float inv = 1.f / sum;
        __syncthreads();

        int e16 = lane & 15, kh = lane >> 4;
        float ox = 0.f, oy = 0.f;
        int kbeg = kh * 75;
        for (int k = kbeg; k < kbeg + 75; ++k) {
            float p = ps[wavei][k];
            uint32 u = Vsu[k * 17 + e16];
            ox += p * b2f((us)u);
            oy += p * b2f((us)(u >> 16));
        }
        ox += __shfl_xor(ox, 16); ox += __shfl_xor(ox, 32);
        oy += __shfl_xor(oy, 16); oy += __shfl_xor(oy, 32);
        if (q < 300 && kh == 0) {
            *(float2*)(sain + (size_t)(t * 300 + q) * 256 + h * 32 + 2 * e16)
                = make_float2(ox * inv, oy * inv);
        }
        __syncthreads();
    }
}

// ---------------------------------------------------------------------------
// aw softmax + deformable bilinear sampling (unchanged — verified)
// ---------------------------------------------------------------------------
__global__ __launch_bounds__(256) void sample_kernel(
        const float* __restrict__ awl,   const float* __restrict__ refp,
        const float* __restrict__ cfo,   const float* __restrict__ ofo,
        const float* __restrict__ soffo, const float* __restrict__ toffo,
        const us* __restrict__ value, float* __restrict__ samp) {
    int b = blockIdx.x;
    int t = b / LQ_;
    int tid = threadIdx.x, h = tid >> 5, d = tid & 31;
    size_t row = (size_t)b;

    float logit = awl[row * 256 + (size_t)tid];
    float mx = logit;
    #pragma unroll
    for (int off = 16; off >= 1; off >>= 1) mx = fmaxf(mx, __shfl_xor(mx, off, 32));
    float e = __expf(logit - mx);
    float s = e;
    #pragma unroll
    for (int off = 16; off >= 1; off >>= 1) s += __shfl_xor(s, off, 32);
    float myw = e / s;

    float soff_my = soffo[row * 256 + (size_t)tid];
    float toff_my = toffo[row * 256 + (size_t)tid];
    float rp_my = (d < 8)  ? refp[row * 8 + d]  : 0.f;
    float cf_my = (d < 8)  ? cfo[row * 8 + d]   : 0.f;
    float of_my = (d < 16) ? ofo[row * 16 + d]  : 0.f;

    float acc = 0.f;
    #pragma unroll
    for (int smp = 0; smp < 32; ++smp) {
        const int l = smp >> 3, j = smp & 7;
        const int Hl = (l == 0) ? 96 : (l == 1) ? 48 : (l == 2) ? 24 : 12;
        const int Wl = (l == 0) ? 128 : (l == 1) ? 64 : (l == 2) ? 32 : 16;
        const int st = (l == 0) ? 0 : (l == 1) ? 12288 : (l == 2) ? 15360 : 16128;
        const float iW = 1.f / (float)Wl, iH = 1.f / (float)Hl;

        float wgt = __shfl(myw, smp, 32);
        float rx = __shfl(rp_my, l * 2 + 0, 32);
        float ry = __shfl(rp_my, l * 2 + 1, 32);
        float lx, ly; int frame;
        if (j < 4) {
            lx = rx + __shfl(cf_my, l * 2 + 0, 32) + __shfl(soff_my, l * 8 + j * 2 + 0, 32) * iW;
            ly = ry + __shfl(cf_my, l * 2 + 1, 32) + __shfl(soff_my, l * 8 + j * 2 + 1, 32) * iH;
            frame = t;
        } else {
            const int wi = (j - 4) >> 1, p = (j - 4) & 1;
            lx = rx + __shfl(of_my, wi * 8 + l * 2 + 0, 32) + __shfl(toff_my, l * 8 + wi * 4 + p * 2 + 0, 32) * iW;
            ly = ry + __shfl(of_my, wi * 8 + l * 2 + 1, 32) + __shfl(toff_my, l * 8 + wi * 4 + p * 2 + 1, 32) * iH;
            frame = t + (wi == 0 ? -1 : 1);
            frame = frame < 0 ? 0 : (frame > T_ - 1 ? T_ - 1 : frame);
        }
        float x = lx * (float)Wl - 0.5f, y = ly * (float)Hl - 0.5f;
        float xf = floorf(x), yf = floorf(y);
        float wx = x - xf, wy = y - yf;
        int x0 = (int)xf, y0 = (int)yf;
        int x1 = x0 + 1, y1 = y0 + 1;
        float vx0 = (x0 >= 0 && x0 < Wl) ? 1.f : 0.f;
        float vx1 = (x1 >= 0 && x1 < Wl) ? 1.f : 0.f;
        float vy0 = (y0 >= 0 && y0 < Hl) ? 1.f : 0.f;
        float vy1 = (y1 >= 0 && y1 < Hl) ? 1.f : 0.f;
        int cx0 = min(max(x0, 0), Wl - 1), cx1 = min(max(x1, 0), Wl - 1);
        int cy0 = min(max(y0, 0), Hl - 1), cy1 = min(max(y1, 0), Hl - 1);
        size_t base = ((size_t)frame * LIN_ + st) * 256 + h * 32 + d;
        float g00 = b2f(value[base + (size_t)(cy0 * Wl + cx0) * 256]);
        float g01 = b2f(value[base + (size_t)(cy0 * Wl + cx1) * 256]);
        float g10 = b2f(value[base + (size_t)(cy1 * Wl + cx0) * 256]);
        float g11 = b2f(value[base + (size_t)(cy1 * Wl + cx1) * 256]);
        float w00 = (1.f - wx) * (1.f - wy) * vx0 * vy0;
        float w01 = wx * (1.f - wy) * vx1 * vy0;
        float w10 = (1.f - wx) * wy * vx0 * vy1;
        float w11 = wx * wy * vx1 * vy1;
        acc += wgt * (g00 * w00 + g01 * w01 + g10 * w10 + g11 * w11);
    }
    samp[row * 256 + (size_t)tid] = acc;
}

// ---------------------------------------------------------------------------
// out = LN(x + y)*g + b ; optional out2 = out + pos. One block per row.
// ---------------------------------------------------------------------------
__global__ __launch_bounds__(256) void ln_kernel(
        const float* __restrict__ x, const float* __restrict__ y,
        const float* __restrict__ g, const float* __restrict__ bb,
        float* __restrict__ out,
        const float* __restrict__ pos, float* __restrict__ out2) {
    int row = blockIdx.x, c = threadIdx.x;
    size_t idx = (size_t)row * 256 + c;
    float v = x[idx] + y[idx];
    float s = v;
    #pragma unroll
    for (int off = 1; off < 64; off <<= 1) s += __shfl_xor(s, off);
    __shared__ float red[4];
    int wv = c >> 6;
    if ((c & 63) == 0) red[wv] = s;
    __syncthreads();
    float mean = (red[0] + red[1] + red[2] + red[3]) * (1.0f / 256.0f);
    float dv = v - mean;
    float s2 = dv * dv;
    #pragma unroll
    for (int off = 1; off < 64; off <<= 1) s2 += __shfl_xor(s2, off);
    __syncthreads();
    if ((c & 63) == 0) red[wv] = s2;
    __syncthreads();
    float var = (red[0] + red[1] + red[2] + red[3]) * (1.0f / 256.0f);
    float o = dv * rsqrtf(var + 1e-5f) * g[c] + bb[c];
    out[idx] = o;
    if (out2) out2[idx] = o + pos[idx];
}

// ---------------------------------------------------------------------------
extern "C" void kernel_launch(void* const* d_in, const int* in_sizes, int n_in,
                              void* d_out, int out_size, void* d_ws, size_t ws_size,
                              hipStream_t stream) {
    (void)in_sizes; (void)n_in; (void)out_size; (void)ws_size;
    typedef const float* cfp;
    cfp tgt   = (cfp)d_in[0];
    cfp qpos  = (cfp)d_in[1];
    cfp refp  = (cfp)d_in[2];
    cfp cfo   = (cfp)d_in[3];
    cfp ofo   = (cfp)d_in[4];
    cfp src   = (cfp)d_in[5];
    cfp in_proj_w = (cfp)d_in[9];
    cfp in_proj_b = (cfp)d_in[10];
    cfp sa_out_w  = (cfp)d_in[11];
    cfp sa_out_b  = (cfp)d_in[12];
    cfp n1g = (cfp)d_in[13], n1b = (cfp)d_in[14];
    cfp n2g = (cfp)d_in[15], n2b = (cfp)d_in[16];
    cfp n3g = (cfp)d_in[17], n3b = (cfp)d_in[18];
    cfp value_w = (cfp)d_in[19], value_b = (cfp)d_in[20];
    cfp soff_w = (cfp)d_in[21], soff_b = (cfp)d_in[22];
    cfp toff_w = (cfp)d_in[23], toff_b = (cfp)d_in[24];
    cfp attn_w = (cfp)d_in[25], attn_b = (cfp)d_in[26];
    cfp cross_w = (cfp)d_in[27], cross_b = (cfp)d_in[28];
    cfp lin1_w = (cfp)d_in[29], lin1_b = (cfp)d_in[30];
    cfp lin2_w = (cfp)d_in[31], lin2_b = (cfp)d_in[32];

    // ---- workspace arena (lifetime-aliased; launches are stream-ordered)
    char* wp = (char*)d_ws;
    const size_t ROWB = (size_t)NQ_ * 256 * 4;
    us* value = (us*)wp;  wp += (size_t)T_ * LIN_ * 256 * 2;   // bf16, 50 MB
    float* bigreg = (float*)wp;  wp += 4 * ROWB;               // qkb|vbuf, then ff1
    float* qkb  = bigreg;                                      // NQ x 512
    float* vbuf = bigreg + (size_t)NQ_ * 512;                  // NQ x 256
    float* ff1  = bigreg;                                      // NQ x 1024
    float* sain   = (float*)wp; wp += ROWB;   float* awl    = sain;
    float* sap    = (float*)wp; wp += ROWB;   float* soffo  = sap;
    float* tgt2   = (float*)wp; wp += ROWB;   float* ff2    = tgt2;
    float* qc     = (float*)wp; wp += ROWB;   float* samp   = qc;
    float* toffo  = (float*)wp; wp += ROWB;
    float* crossp = (float*)wp; wp += ROWB;
    float* tgt3   = (float*)wp; wp += ROWB;
    us* wb = (us*)wp; wp += (size_t)WTOTAL * 2;                // bf16 weights, 2.2 MB

    dim3 blk(256);
    const int mb = (NQ_ + 63) / 64;  // 29

    // D0: one-time weight fp32->bf16 conversion
    cvt_kernel<<<dim3(128, 9), blk, 0, stream>>>(
        value_w, in_proj_w, sa_out_w, soff_w, toff_w, attn_w, cross_w,
        lin1_w, lin2_w, wb);
    // D1: value projection (1530 blocks) + qkv projection (348 blocks) fused
    vqkv_kernel<<<dim3(1530 + 348), blk, 0, stream>>>(
        src, wb + WOFF_VAL, value_b, value, tgt, qpos, wb + WOFF_IN, in_proj_b,
        qkb, vbuf);
    // D2: self attention
    attn_kernel<<<dim3(T_ * NH_, 10), blk, 0, stream>>>(qkb, vbuf, sain);
    // D3: sa-out projection
    gemm_std<false><<<dim3(mb, 4), blk, 0, stream>>>(sain, wb + WOFF_SA, sa_out_b, sap, NQ_, 256, 256);
    // D4: tgt2 = LN(tgt + sa); qc = tgt2 + qpos
    ln_kernel<<<dim3(NQ_), blk, 0, stream>>>(tgt, sap, n2g, n2b, tgt2, qpos, qc);
    // D5: soff/toff/attn-weight projections
    gemm_proj3<<<dim3(mb, 12), blk, 0, stream>>>(qc, wb + WOFF_SOFF, soff_b,
                                                 wb + WOFF_TOFF, toff_b,
                                                 wb + WOFF_ATTN, attn_b,
                                                 soffo, toffo, awl);
    // D6: fused aw-softmax + deformable sampling
    sample_kernel<<<dim3(NQ_), blk, 0, stream>>>(awl, refp, cfo, ofo, soffo, toffo, value, samp);
    // D7: cross projection
    gemm_std<false><<<dim3(mb, 4), blk, 0, stream>>>(samp, wb + WOFF_CROSS, cross_b, crossp, NQ_, 256, 256);
    // D8: tgt3 = LN(tgt2 + cross)
    ln_kernel<<<dim3(NQ_), blk, 0, stream>>>(tgt2, crossp, n1g, n1b, tgt3, nullptr, nullptr);
    // D9: ffn1 (relu)
    gemm_std<true><<<dim3(mb, 16), blk, 0, stream>>>(tgt3, wb + WOFF_LIN1, lin1_b, ff1, NQ_, 1024, 256);
    // D10: ffn2
    gemm_std<false><<<dim3(mb, 4), blk, 0, stream>>>(ff1, wb + WOFF_LIN2, lin2_b, ff2, NQ_, 256, 1024);
    // D11: out = LN(tgt3 + ff)
    ln_kernel<<<dim3(NQ_), blk, 0, stream>>>(tgt3, ff2, n3g, n3b, (float*)d_out, nullptr, nullptr);
}